// Round 17
// baseline (1595.277 us; speedup 1.0000x reference)
//
#include <hip/hip_runtime.h>
#include <stdint.h>

#define B_ 128
#define S_ 512
#define I_ 128
#define H_ 256

typedef short bf16x8 __attribute__((ext_vector_type(8)));
typedef short bf16x4 __attribute__((ext_vector_type(4)));
typedef float f32x4  __attribute__((ext_vector_type(4)));

__device__ __forceinline__ short f2bf(float f){
  unsigned u = __float_as_uint(f);
  u = (u + 0x7FFFu + ((u >> 16) & 1u)) >> 16;
  return (short)u;
}
__device__ __forceinline__ float bf2f(unsigned short u){
  return __uint_as_float(((unsigned)u) << 16);
}
__device__ __forceinline__ float sigmoidf_(float x){
  float e = __expf(-x);
  return __fdividef(1.f, 1.f + e);
}
__device__ __forceinline__ float tanhf_(float x){
  x = fminf(fmaxf(x, -10.f), 10.f);
  float e = __expf(2.f * x);
  return __fdividef(e - 1.f, e + 1.f);
}
__device__ __forceinline__ void bar_lds(){
  asm volatile("s_waitcnt lgkmcnt(0)" ::: "memory");
  __builtin_amdgcn_s_barrier();
}
#define MF(A, B, C) __builtin_amdgcn_mfma_f32_16x16x32_bf16((A), (B), (C), 0, 0, 0)

// ---------------- prep ---------------------------------------------------------
__global__ __launch_bounds__(256) void prep_compute(
    const float* __restrict__ W_in, const float* __restrict__ b_in,
    const float* __restrict__ Wz, const float* __restrict__ bz,
    const float* __restrict__ Wr, const float* __restrict__ br,
    const float* __restrict__ Wn, const float* __restrict__ bn,
    float* __restrict__ WcT, float* __restrict__ bc, float* __restrict__ bcat1)
{
  int id = blockIdx.x * 256 + threadIdx.x;
  if (id < 98304){
    int i = id / 768, gcol = id % 768;
    int g = gcol >> 8, n = gcol & 255;
    const float* Wg = (g == 0) ? Wz : (g == 1) ? Wr : Wn;
    float s = 0.f;
    for (int j = 0; j < 256; j++) s += W_in[i * 256 + j] * Wg[j * 256 + n];
    WcT[i * 768 + gcol] = s;
  } else if (id < 99072){
    int gcol = id - 98304;
    int g = gcol >> 8, n = gcol & 255;
    const float* Wg = (g == 0) ? Wz : (g == 1) ? Wr : Wn;
    const float* bg = (g == 0) ? bz : (g == 1) ? br : bn;
    float s = 0.f;
    for (int j = 0; j < 256; j++) s += b_in[j] * Wg[j * 256 + n];
    bc[gcol] = s + bg[n];
  } else if (id < 99840){
    int gcol = id - 99072;
    int g = gcol >> 8, n = gcol & 255;
    const float* bg = (g == 0) ? bz : (g == 1) ? br : bn;
    bcat1[gcol] = bg[256 + n];
  }
}

// ---------------- fragment packing --------------------------------------------
__global__ __launch_bounds__(256) void pack_wc(short* __restrict__ dst, const float* __restrict__ WcT)
{
  int id = blockIdx.x * 256 + threadIdx.x;
  int j = id & 7, l = (id >> 3) & 63, kt = (id >> 9) & 3, nt = id >> 11;
  int k = kt * 32 + (l >> 4) * 8 + j;
  int gcol = nt * 16 + (l & 15);
  dst[id] = f2bf(WcT[k * 768 + gcol]);
}

__global__ __launch_bounds__(256) void pack_top(short* __restrict__ dst,
    const float* __restrict__ Wz, const float* __restrict__ Wr, const float* __restrict__ Wn)
{
  int id = blockIdx.x * 256 + threadIdx.x;
  int j = id & 7, l = (id >> 3) & 63, kt = (id >> 9) & 7, nt = id >> 12;
  int k = kt * 32 + (l >> 4) * 8 + j;
  int gcol = nt * 16 + (l & 15);
  int g = gcol >> 8, n = gcol & 255;
  const float* W = (g == 0) ? Wz : (g == 1) ? Wr : Wn;
  dst[id] = f2bf(W[(size_t)(512 + k) * 256 + n]);
}

__global__ __launch_bounds__(256) void pack_zr(short* __restrict__ dst,
    const float* __restrict__ Wz, const float* __restrict__ Wr, int layer)
{
  int id = blockIdx.x * 256 + threadIdx.x;
  int j = id & 7, l = (id >> 3) & 63, kt = (id >> 9) & 7, nt = id >> 12;
  int k = kt * 32 + (l >> 4) * 8 + j;
  int n = (nt & 15) * 16 + (l & 15);
  const float* W = (nt < 16) ? Wz : Wr;
  dst[id] = f2bf(W[((size_t)layer * 512 + 256 + k) * 256 + n]);
}

__global__ __launch_bounds__(256) void pack_n(short* __restrict__ dst,
    const float* __restrict__ Wn, int layer)
{
  int id = blockIdx.x * 256 + threadIdx.x;
  int j = id & 7, l = (id >> 3) & 63, kt = (id >> 9) & 7, nt = id >> 12;
  int k = kt * 32 + (l >> 4) * 8 + j;
  int n = nt * 16 + (l & 15);
  dst[id] = f2bf(Wn[((size_t)layer * 512 + 256 + k) * 256 + n]);
}

// ---------------- G0 GEMM: C[M,768] = x[M,128] @ WcF + bc ----------------------
__global__ __launch_bounds__(256) void gemm_g0(
    const float* __restrict__ Ap, const short* __restrict__ BF,
    const float* __restrict__ bias, short* __restrict__ C)
{
  const int tid = threadIdx.x, w = tid >> 6, l = tid & 63;
  const int m0 = blockIdx.x * 64 + w * 16;
  const int nb = blockIdx.y;
  const int K = 128;
  f32x4 zero4 = {0.f, 0.f, 0.f, 0.f};
  f32x4 acc[8];
#pragma unroll
  for (int nt = 0; nt < 8; nt++) acc[nt] = zero4;
#pragma unroll
  for (int kt = 0; kt < 4; kt++){
    const float* A = Ap + (size_t)(m0 + (l & 15)) * K + kt * 32 + (l >> 4) * 8;
    f32x4 a0 = *(const f32x4*)A;
    f32x4 a1 = *(const f32x4*)(A + 4);
    bf16x8 af;
    af[0] = f2bf(a0[0]); af[1] = f2bf(a0[1]); af[2] = f2bf(a0[2]); af[3] = f2bf(a0[3]);
    af[4] = f2bf(a1[0]); af[5] = f2bf(a1[1]); af[6] = f2bf(a1[2]); af[7] = f2bf(a1[3]);
#pragma unroll
    for (int nt = 0; nt < 8; nt++){
      bf16x8 bf = *(const bf16x8*)(BF + (size_t)(((nb * 8 + nt) * 4 + kt) * 64 + l) * 8);
      acc[nt] = MF(af, bf, acc[nt]);
    }
  }
#pragma unroll
  for (int nt = 0; nt < 8; nt++){
    int col = nb * 128 + nt * 16 + (l & 15);
    float bv = bias[col];
#pragma unroll
    for (int rr = 0; rr < 4; rr++){
      int mrow = m0 + (l >> 4) * 4 + rr;
      C[(size_t)mrow * 768 + col] = f2bf(acc[nt][rr] + bv);
    }
  }
}

// ---------------- repack Gbuf -> per-thread 6-value chunks (layer0) ------------
__global__ __launch_bounds__(256) void repack6(const unsigned short* __restrict__ Gbuf,
                                               short* __restrict__ GpA4, unsigned* __restrict__ GpB2)
{
  int id = blockIdx.x * 256 + threadIdx.x;
  int cix = id & 15, wv = (id >> 4) & 7, t = (id >> 7) & 511, row = id >> 16;
  short v[6];
#pragma unroll
  for (int i = 0; i < 2; i++)
#pragma unroll
    for (int g = 0; g < 3; g++)
      v[i * 3 + g] =
        (short)Gbuf[((size_t)row * 512 + t) * 768 + g * 256 + i * 128 + wv * 16 + cix];
  bf16x4 a = {v[0], v[1], v[2], v[3]};
  *(bf16x4*)(GpA4 + (size_t)id * 4) = a;
  GpB2[id] = (unsigned)(unsigned short)v[4] | ((unsigned)(unsigned short)v[5] << 16);
}

// ---------------- fused dual-layer persistent kernel ---------------------------
// 256 blocks x 512 threads, co-resident. L0 -> L1 only.
// R16: consumer weight-reg recycling. Per chunk:
//   GEMM phase: weight arrays are DEAD (reloaded later) -> ~190 free VGPRs used
//   for a deep pipeline: all 8 A-frags upfront + double-buffered B (12 frags).
//   Then weights RELOADED from L2/L3 (live range = steps only; LICM defeated
//   via opaque-pointer asm), and 16 steps run in the R8 all-reg form (no wnL).
__global__ __launch_bounds__(512, 1) void fused_recur(
    const short* __restrict__ GpA4, const unsigned* __restrict__ GpB2,
    const short* __restrict__ WZR0F, const short* __restrict__ WN0F,
    const short* __restrict__ WZR1F, const short* __restrict__ WN1F,
    const short* __restrict__ W1TF, const float* __restrict__ bcat1,
    short* __restrict__ pipe, float* __restrict__ out,
    float* __restrict__ finals, unsigned* __restrict__ flags)
{
  __shared__ __align__(16) char  ldsb[4096];    // h/rA state + zero regions
  __shared__ __align__(16) short p1L[12288];    // layer1 P1 chunk [w][16t][16cix][6]

  const int tid = threadIdx.x;
  const int w = tid >> 6, l = tid & 63;
  const int cix = l & 15, lk = l >> 4;
  const f32x4 Z4 = {0.f, 0.f, 0.f, 0.f};

  *(uint64_t*)(ldsb + tid * 8) = 0ull;

  const int A0 = (cix == 0) ? (lk << 4) : 1024;   // bcast zero for cix>0
  const int col0 = w * 16 + cix, col1 = col0 + 128;
  const int oA00 = col0 * 2, oA10 = col1 * 2;
  float h00 = 0.f, h10 = 0.f;

#define AF_ZR(KT) (*(const bf16x8*)(ldsb + A0 + (KT) * 64))
#define AF_N(KT)  (*(const bf16x8*)(ldsb + A0 + (KT) * 64 + 2048))

// shared step body: zr matmul (4-deep af rotation) -> gates -> rA write ->
// barrier -> n matmul (2-deep, weights in regs) -> h update -> SINK
#define STEP_CORE(GATE_CODE, SINK_CODE) do { \
    bf16x8 x0 = AF_ZR(0), x1 = AF_ZR(1), x2 = AF_ZR(2), x3 = AF_ZR(3); \
    f32x4 az0 = Z4, az1 = Z4, ar0 = Z4, ar1 = Z4; \
    __builtin_amdgcn_s_setprio(1); \
    az0 = MF(x0, wzr[0][0], az0); az1 = MF(x0, wzr[1][0], az1); \
    ar0 = MF(x0, wzr[2][0], ar0); ar1 = MF(x0, wzr[3][0], ar1); x0 = AF_ZR(4); \
    az0 = MF(x1, wzr[0][1], az0); az1 = MF(x1, wzr[1][1], az1); \
    ar0 = MF(x1, wzr[2][1], ar0); ar1 = MF(x1, wzr[3][1], ar1); x1 = AF_ZR(5); \
    az0 = MF(x2, wzr[0][2], az0); az1 = MF(x2, wzr[1][2], az1); \
    ar0 = MF(x2, wzr[2][2], ar0); ar1 = MF(x2, wzr[3][2], ar1); x2 = AF_ZR(6); \
    az0 = MF(x3, wzr[0][3], az0); az1 = MF(x3, wzr[1][3], az1); \
    ar0 = MF(x3, wzr[2][3], ar0); ar1 = MF(x3, wzr[3][3], ar1); x3 = AF_ZR(7); \
    az0 = MF(x0, wzr[0][4], az0); az1 = MF(x0, wzr[1][4], az1); \
    ar0 = MF(x0, wzr[2][4], ar0); ar1 = MF(x0, wzr[3][4], ar1); \
    az0 = MF(x1, wzr[0][5], az0); az1 = MF(x1, wzr[1][5], az1); \
    ar0 = MF(x1, wzr[2][5], ar0); ar1 = MF(x1, wzr[3][5], ar1); \
    az0 = MF(x2, wzr[0][6], az0); az1 = MF(x2, wzr[1][6], az1); \
    ar0 = MF(x2, wzr[2][6], ar0); ar1 = MF(x2, wzr[3][6], ar1); \
    az0 = MF(x3, wzr[0][7], az0); az1 = MF(x3, wzr[1][7], az1); \
    ar0 = MF(x3, wzr[2][7], ar0); ar1 = MF(x3, wzr[3][7], ar1); \
    __builtin_amdgcn_s_setprio(0); \
    float gn00 = 0.f, gn10 = 0.f, zv00 = 0.f, zv10 = 0.f; \
    if (lk == 0){ \
      float gz00, gr00, gz10, gr10; \
      GATE_CODE \
      zv00 = sigmoidf_(az0[0] + gz00); zv10 = sigmoidf_(az1[0] + gz10); \
      float rv00 = sigmoidf_(ar0[0] + gr00), rv10 = sigmoidf_(ar1[0] + gr10); \
      *(short*)(ldsb + 2048 + oA00) = f2bf(rv00 * h00); \
      *(short*)(ldsb + 2048 + oA10) = f2bf(rv10 * h10); \
    } \
    bar_lds(); \
    bf16x8 y0 = AF_N(0), y1 = AF_N(1); \
    f32x4 an0 = Z4, an1 = Z4; \
    __builtin_amdgcn_s_setprio(1); \
    an0 = MF(y0, wn[0][0], an0); an1 = MF(y0, wn[1][0], an1); y0 = AF_N(2); \
    an0 = MF(y1, wn[0][1], an0); an1 = MF(y1, wn[1][1], an1); y1 = AF_N(3); \
    an0 = MF(y0, wn[0][2], an0); an1 = MF(y0, wn[1][2], an1); y0 = AF_N(4); \
    an0 = MF(y1, wn[0][3], an0); an1 = MF(y1, wn[1][3], an1); y1 = AF_N(5); \
    an0 = MF(y0, wn[0][4], an0); an1 = MF(y0, wn[1][4], an1); y0 = AF_N(6); \
    an0 = MF(y1, wn[0][5], an0); an1 = MF(y1, wn[1][5], an1); y1 = AF_N(7); \
    an0 = MF(y0, wn[0][6], an0); an1 = MF(y0, wn[1][6], an1); \
    an0 = MF(y1, wn[0][7], an0); an1 = MF(y1, wn[1][7], an1); \
    __builtin_amdgcn_s_setprio(0); \
    if (lk == 0){ \
      float nv00 = tanhf_(an0[0] + gn00), nv10 = tanhf_(an1[0] + gn10); \
      h00 = (1.f - zv00) * nv00 + zv00 * h00; \
      h10 = (1.f - zv10) * nv10 + zv10 * h10; \
      *(short*)(ldsb + oA00) = f2bf(h00); \
      *(short*)(ldsb + oA10) = f2bf(h10); \
      SINK_CODE \
    } \
    bar_lds(); \
  } while (0)

  if (blockIdx.x < 128){
    // =================== layer 0 (producer) ===================
    const int r0 = blockIdx.x;
    const int chunkBase = blockIdx.x * 65536 + w * 16 + cix;
    bf16x8 wzr[4][8], wn[2][8];
#pragma unroll
    for (int i = 0; i < 4; i++)
#pragma unroll
      for (int kt = 0; kt < 8; kt++)
        wzr[i][kt] = *(const bf16x8*)(WZR0F + (size_t)((((w + 8 * i) * 8 + kt) * 64 + l) * 8));
#pragma unroll
    for (int i = 0; i < 2; i++)
#pragma unroll
      for (int kt = 0; kt < 8; kt++)
        wn[i][kt] = *(const bf16x8*)(WN0F + (size_t)((((w + 8 * i) * 8 + kt) * 64 + l) * 8));
    __syncthreads();

    bf16x4 rgA0{}, rgA1{};
    unsigned rgB0 = 0, rgB1 = 0;
    if (lk == 0){
      rgA0 = *(const bf16x4*)(GpA4 + (size_t)chunkBase * 4);
      rgB0 = GpB2[chunkBase];
      rgA1 = *(const bf16x4*)(GpA4 + (size_t)(chunkBase + 128) * 4);
      rgB1 = GpB2[chunkBase + 128];
    }

#define GATE0(T, RGA, RGB) \
      gz00 = bf2f((unsigned short)RGA[0]); gr00 = bf2f((unsigned short)RGA[1]); \
      gn00 = bf2f((unsigned short)RGA[2]); \
      gz10 = bf2f((unsigned short)RGA[3]); \
      gr10 = bf2f((unsigned short)(RGB & 0xffffu)); \
      gn10 = bf2f((unsigned short)(RGB >> 16)); \
      { int tn = (T) + 2; if (tn >= S_) tn = (T); \
        size_t ch = (size_t)chunkBase + (size_t)tn * 128; \
        RGA = *(const bf16x4*)(GpA4 + ch * 4); \
        RGB = GpB2[ch]; }
#define SINK0(T) \
      { size_t ob = ((size_t)r0 * S_ + (T)) * H_; \
        pipe[ob + col0] = f2bf(h00); \
        pipe[ob + col1] = f2bf(h10); }

#pragma unroll 1
    for (int t = 0; t < S_; t += 2){
      STEP_CORE(GATE0(t, rgA0, rgB0), SINK0(t));
      STEP_CORE(GATE0(t + 1, rgA1, rgB1), SINK0(t + 1));
      if ((t & 15) == 14){
        __syncthreads();   // drains each wave's vmcnt: all pipe stores in L2
        if (tid == 0)
          __hip_atomic_store(&flags[r0], (unsigned)((t + 2) >> 4),
                             __ATOMIC_RELEASE, __HIP_MEMORY_SCOPE_AGENT);
      }
    }
#undef GATE0
#undef SINK0
    if (lk == 0){
      finals[(size_t)r0 * H_ + col0] = h00;
      finals[(size_t)r0 * H_ + col1] = h10;
    }
  } else {
    // =================== layer 1 (consumer) ===================
    const int b = blockIdx.x - 128;
    // W1top streamed frag bases: nt order [z0,r0,n0,z1,r1,n1]
    const short* wt0 = W1TF + (size_t)(w)      * 4096 + l * 8;
    const short* wt1 = W1TF + (size_t)(16 + w) * 4096 + l * 8;
    const short* wt2 = W1TF + (size_t)(32 + w) * 4096 + l * 8;
    const short* wt3 = W1TF + (size_t)(8 + w)  * 4096 + l * 8;
    const short* wt4 = W1TF + (size_t)(24 + w) * 4096 + l * 8;
    const short* wt5 = W1TF + (size_t)(40 + w) * 4096 + l * 8;
    const float bb0 = bcat1[0 * 256 + col0];
    const float bb1 = bcat1[1 * 256 + col0];
    const float bb2 = bcat1[2 * 256 + col0];
    const float bb3 = bcat1[0 * 256 + col1];
    const float bb4 = bcat1[1 * 256 + col1];
    const float bb5 = bcat1[2 * 256 + col1];
    short* p1Lw = p1L + w * 1536;   // 16t*16cix*6
    __syncthreads();

    // opaque weight pointers: redefined each chunk -> loads can't be hoisted,
    // so the 192 weight regs are DEAD during the GEMM phase (no spills)
    unsigned long long wzq = (unsigned long long)WZR1F;
    unsigned long long wnq = (unsigned long long)WN1F;

#pragma unroll 1
    for (int c = 0; c < 32; c++){
      if (tid == 0){
        unsigned target = (unsigned)(c + 1);
        int guard = 0;
        while (__hip_atomic_load(&flags[b], __ATOMIC_ACQUIRE, __HIP_MEMORY_SCOPE_AGENT) < target){
          __builtin_amdgcn_s_sleep(4);
          if (++guard > (1 << 20)) break;   // bounded: bug -> wrong answer, not hang
        }
      }
      __syncthreads();

      // ---- P1 chunk GEMM (deep-pipelined; weight regs dead here) ----
      // rows = 16 timesteps (full M), K=256, 6 N-tiles per wave
      {
        const short* hp = pipe + ((size_t)b * 512 + c * 16 + cix) * 256 + lk * 8;
        bf16x8 A0 = *(const bf16x8*)(hp + 0 * 32), A1 = *(const bf16x8*)(hp + 1 * 32);
        bf16x8 A2 = *(const bf16x8*)(hp + 2 * 32), A3 = *(const bf16x8*)(hp + 3 * 32);
        bf16x8 A4 = *(const bf16x8*)(hp + 4 * 32), A5 = *(const bf16x8*)(hp + 5 * 32);
        bf16x8 A6 = *(const bf16x8*)(hp + 6 * 32), A7 = *(const bf16x8*)(hp + 7 * 32);
        bf16x8 c00 = *(const bf16x8*)(wt0),       c01 = *(const bf16x8*)(wt1);
        bf16x8 c02 = *(const bf16x8*)(wt2),       c03 = *(const bf16x8*)(wt3);
        bf16x8 c04 = *(const bf16x8*)(wt4),       c05 = *(const bf16x8*)(wt5);
        bf16x8 c10 = *(const bf16x8*)(wt0 + 512), c11 = *(const bf16x8*)(wt1 + 512);
        bf16x8 c12 = *(const bf16x8*)(wt2 + 512), c13 = *(const bf16x8*)(wt3 + 512);
        bf16x8 c14 = *(const bf16x8*)(wt4 + 512), c15 = *(const bf16x8*)(wt5 + 512);
        f32x4 p0 = Z4, p1 = Z4, p2 = Z4, p3 = Z4, p4 = Z4, p5 = Z4;
#define GSTEP(AX, CB0, CB1, CB2, CB3, CB4, CB5) \
        p0 = MF(AX, CB0, p0); p1 = MF(AX, CB1, p1); p2 = MF(AX, CB2, p2); \
        p3 = MF(AX, CB3, p3); p4 = MF(AX, CB4, p4); p5 = MF(AX, CB5, p5);
#define GRELOAD(CB0, CB1, CB2, CB3, CB4, CB5, KT) \
        CB0 = *(const bf16x8*)(wt0 + (KT) * 512); CB1 = *(const bf16x8*)(wt1 + (KT) * 512); \
        CB2 = *(const bf16x8*)(wt2 + (KT) * 512); CB3 = *(const bf16x8*)(wt3 + (KT) * 512); \
        CB4 = *(const bf16x8*)(wt4 + (KT) * 512); CB5 = *(const bf16x8*)(wt5 + (KT) * 512);
        GSTEP(A0, c00, c01, c02, c03, c04, c05)  GRELOAD(c00, c01, c02, c03, c04, c05, 2)
        GSTEP(A1, c10, c11, c12, c13, c14, c15)  GRELOAD(c10, c11, c12, c13, c14, c15, 3)
        GSTEP(A2, c00, c01, c02, c03, c04, c05)  GRELOAD(c00, c01, c02, c03, c04, c05, 4)
        GSTEP(A3, c10, c11, c12, c13, c14, c15)  GRELOAD(c10, c11, c12, c13, c14, c15, 5)
        GSTEP(A4, c00, c01, c02, c03, c04, c05)  GRELOAD(c00, c01, c02, c03, c04, c05, 6)
        GSTEP(A5, c10, c11, c12, c13, c14, c15)  GRELOAD(c10, c11, c12, c13, c14, c15, 7)
        GSTEP(A6, c00, c01, c02, c03, c04, c05)
        GSTEP(A7, c10, c11, c12, c13, c14, c15)
#undef GSTEP
#undef GRELOAD
        // epilogue -> p1L (bf16 pairs), layout [t][cix][6]
#pragma unroll
        for (int r = 0; r < 4; r++){
          int tl = lk * 4 + r;
          int base = (tl * 16 + cix) * 6;
          unsigned u0 = (unsigned)(unsigned short)f2bf(p0[r]) | ((unsigned)(unsigned short)f2bf(p1[r]) << 16);
          unsigned u1 = (unsigned)(unsigned short)f2bf(p2[r]) | ((unsigned)(unsigned short)f2bf(p3[r]) << 16);
          unsigned u2 = (unsigned)(unsigned short)f2bf(p4[r]) | ((unsigned)(unsigned short)f2bf(p5[r]) << 16);
          *(unsigned*)(p1Lw + base)     = u0;
          *(unsigned*)(p1Lw + base + 2) = u1;
          *(unsigned*)(p1Lw + base + 4) = u2;
        }
      }

      // ---- reload weights (live range: steps only; LICM defeated) ----
      asm volatile("" : "+s"(wzq), "+s"(wnq));
      const short* wzp = (const short*)wzq;
      const short* wnp = (const short*)wnq;
      bf16x8 wzr[4][8], wn[2][8];
#pragma unroll
      for (int i = 0; i < 4; i++)
#pragma unroll
        for (int kt = 0; kt < 8; kt++)
          wzr[i][kt] = *(const bf16x8*)(wzp + (size_t)((((w + 8 * i) * 8 + kt) * 64 + l) * 8));
#pragma unroll
      for (int i = 0; i < 2; i++)
#pragma unroll
        for (int kt = 0; kt < 8; kt++)
          wn[i][kt] = *(const bf16x8*)(wnp + (size_t)((((w + 8 * i) * 8 + kt) * 64 + l) * 8));

      // ---- 16 recurrence steps (all-reg weights, R8 form) ----
#pragma unroll 1
      for (int ts = 0; ts < 16; ts++){
        int T = c * 16 + ts;
#define GATE1 \
        { const short* pb = p1Lw + (ts * 16 + cix) * 6; \
          unsigned u0 = *(const unsigned*)(pb); \
          unsigned u1 = *(const unsigned*)(pb + 2); \
          unsigned u2 = *(const unsigned*)(pb + 4); \
          gz00 = bf2f((unsigned short)(u0 & 0xffffu)) + bb0; \
          gr00 = bf2f((unsigned short)(u0 >> 16)) + bb1; \
          gn00 = bf2f((unsigned short)(u1 & 0xffffu)) + bb2; \
          gz10 = bf2f((unsigned short)(u1 >> 16)) + bb3; \
          gr10 = bf2f((unsigned short)(u2 & 0xffffu)) + bb4; \
          gn10 = bf2f((unsigned short)(u2 >> 16)) + bb5; }
#define SINK1 \
        { size_t ob = ((size_t)b * S_ + T) * H_; \
          out[ob + col0] = h00; \
          out[ob + col1] = h10; }
        STEP_CORE(GATE1, SINK1);
#undef GATE1
#undef SINK1
      }
    }
    if (lk == 0){
      finals[32768 + (size_t)b * H_ + col0] = h00;
      finals[32768 + (size_t)b * H_ + col1] = h10;
    }
  }
#undef STEP_CORE
#undef AF_ZR
#undef AF_N
}

// ---------------- launcher ----------------------------------------------------
extern "C" void kernel_launch(void* const* d_in, const int* in_sizes, int n_in,
                              void* d_out, int out_size, void* d_ws, size_t ws_size,
                              hipStream_t stream)
{
  (void)in_sizes; (void)n_in; (void)out_size; (void)ws_size;
  const float* x    = (const float*)d_in[0];
  const float* W_in = (const float*)d_in[1];
  const float* b_in = (const float*)d_in[2];
  const float* Wz   = (const float*)d_in[3];
  const float* bz   = (const float*)d_in[4];
  const float* Wr   = (const float*)d_in[5];
  const float* br   = (const float*)d_in[6];
  const float* Wn   = (const float*)d_in[7];
  const float* bn   = (const float*)d_in[8];
  float* out = (float*)d_out;

  char* ws = (char*)d_ws;
  short*    Gbuf  = (short*)(ws + 0);            // [65536][768] bf16 (96MB)
  short*    GpA4  = (short*)(ws + 100663296);    // 8.4M chunks * 8B (64MB)
  unsigned* GpB2  = (unsigned*)(ws + 167772160); // 8.4M chunks * 4B (32MB)
  float* WcT   = (float*)(ws + 201326592);
  float* bc    = (float*)(ws + 201719808);
  float* bcat1 = (float*)(ws + 201722880);
  short* WCF   = (short*)(ws + 201725952);
  short* W1TF  = (short*)(ws + 201922560);
  short* WZR0  = (short*)(ws + 202315776);
  short* WN0   = (short*)(ws + 202577920);
  short* WZR1  = (short*)(ws + 202708992);
  short* WN1   = (short*)(ws + 202971136);
  short* pipe  = (short*)(ws + 203102208);       // h0 bf16 [b][t][256] (32MB)
  unsigned* flags = (unsigned*)(ws + 236656640); // [128]

  prep_compute<<<390, 256, 0, stream>>>(W_in, b_in, Wz, bz, Wr, br, Wn, bn, WcT, bc, bcat1);
  pack_wc <<<384, 256, 0, stream>>>(WCF, WcT);
  pack_top<<<768, 256, 0, stream>>>(W1TF, Wz, Wr, Wn);
  pack_zr <<<512, 256, 0, stream>>>(WZR0, Wz, Wr, 0);
  pack_n  <<<256, 256, 0, stream>>>(WN0, Wn, 0);
  pack_zr <<<512, 256, 0, stream>>>(WZR1, Wz, Wr, 1);
  pack_n  <<<256, 256, 0, stream>>>(WN1, Wn, 1);

  gemm_g0<<<dim3(1024, 6), 256, 0, stream>>>(x, WCF, bc, Gbuf);
  repack6<<<32768, 256, 0, stream>>>((const unsigned short*)Gbuf, GpA4, GpB2);
  hipMemsetAsync(flags, 0, 128 * sizeof(unsigned), stream);
  fused_recur<<<256, 512, 0, stream>>>(GpA4, GpB2, WZR0, WN0, WZR1, WN1, W1TF, bcat1,
                                       pipe, out, out + 16777216, flags);
}

// Round 18
// 1294.607 us; speedup vs baseline: 1.2322x; 1.2322x over previous
//
#include <hip/hip_runtime.h>
#include <stdint.h>

#define B_ 128
#define S_ 512
#define I_ 128
#define H_ 256

typedef short bf16x8 __attribute__((ext_vector_type(8)));
typedef short bf16x4 __attribute__((ext_vector_type(4)));
typedef float f32x4  __attribute__((ext_vector_type(4)));

__device__ __forceinline__ short f2bf(float f){
  unsigned u = __float_as_uint(f);
  u = (u + 0x7FFFu + ((u >> 16) & 1u)) >> 16;
  return (short)u;
}
__device__ __forceinline__ float bf2f(unsigned short u){
  return __uint_as_float(((unsigned)u) << 16);
}
__device__ __forceinline__ float sigmoidf_(float x){
  float e = __expf(-x);
  return __fdividef(1.f, 1.f + e);
}
__device__ __forceinline__ float tanhf_(float x){
  x = fminf(fmaxf(x, -10.f), 10.f);
  float e = __expf(2.f * x);
  return __fdividef(e - 1.f, e + 1.f);
}
__device__ __forceinline__ void bar_lds(){
  asm volatile("s_waitcnt lgkmcnt(0)" ::: "memory");
  __builtin_amdgcn_s_barrier();
}
#define MF(A, B, C) __builtin_amdgcn_mfma_f32_16x16x32_bf16((A), (B), (C), 0, 0, 0)

// ---------------- prep ---------------------------------------------------------
__global__ __launch_bounds__(256) void prep_compute(
    const float* __restrict__ W_in, const float* __restrict__ b_in,
    const float* __restrict__ Wz, const float* __restrict__ bz,
    const float* __restrict__ Wr, const float* __restrict__ br,
    const float* __restrict__ Wn, const float* __restrict__ bn,
    float* __restrict__ WcT, float* __restrict__ bc, float* __restrict__ bcat1)
{
  int id = blockIdx.x * 256 + threadIdx.x;
  if (id < 98304){
    int i = id / 768, gcol = id % 768;
    int g = gcol >> 8, n = gcol & 255;
    const float* Wg = (g == 0) ? Wz : (g == 1) ? Wr : Wn;
    float s = 0.f;
    for (int j = 0; j < 256; j++) s += W_in[i * 256 + j] * Wg[j * 256 + n];
    WcT[i * 768 + gcol] = s;
  } else if (id < 99072){
    int gcol = id - 98304;
    int g = gcol >> 8, n = gcol & 255;
    const float* Wg = (g == 0) ? Wz : (g == 1) ? Wr : Wn;
    const float* bg = (g == 0) ? bz : (g == 1) ? br : bn;
    float s = 0.f;
    for (int j = 0; j < 256; j++) s += b_in[j] * Wg[j * 256 + n];
    bc[gcol] = s + bg[n];
  } else if (id < 99840){
    int gcol = id - 99072;
    int g = gcol >> 8, n = gcol & 255;
    const float* bg = (g == 0) ? bz : (g == 1) ? br : bn;
    bcat1[gcol] = bg[256 + n];
  }
}

// ---------------- fragment packing --------------------------------------------
__global__ __launch_bounds__(256) void pack_wc(short* __restrict__ dst, const float* __restrict__ WcT)
{
  int id = blockIdx.x * 256 + threadIdx.x;
  int j = id & 7, l = (id >> 3) & 63, kt = (id >> 9) & 3, nt = id >> 11;
  int k = kt * 32 + (l >> 4) * 8 + j;
  int gcol = nt * 16 + (l & 15);
  dst[id] = f2bf(WcT[k * 768 + gcol]);
}

__global__ __launch_bounds__(256) void pack_top(short* __restrict__ dst,
    const float* __restrict__ Wz, const float* __restrict__ Wr, const float* __restrict__ Wn)
{
  int id = blockIdx.x * 256 + threadIdx.x;
  int j = id & 7, l = (id >> 3) & 63, kt = (id >> 9) & 7, nt = id >> 12;
  int k = kt * 32 + (l >> 4) * 8 + j;
  int gcol = nt * 16 + (l & 15);
  int g = gcol >> 8, n = gcol & 255;
  const float* W = (g == 0) ? Wz : (g == 1) ? Wr : Wn;
  dst[id] = f2bf(W[(size_t)(512 + k) * 256 + n]);
}

__global__ __launch_bounds__(256) void pack_zr(short* __restrict__ dst,
    const float* __restrict__ Wz, const float* __restrict__ Wr, int layer)
{
  int id = blockIdx.x * 256 + threadIdx.x;
  int j = id & 7, l = (id >> 3) & 63, kt = (id >> 9) & 7, nt = id >> 12;
  int k = kt * 32 + (l >> 4) * 8 + j;
  int n = (nt & 15) * 16 + (l & 15);
  const float* W = (nt < 16) ? Wz : Wr;
  dst[id] = f2bf(W[((size_t)layer * 512 + 256 + k) * 256 + n]);
}

__global__ __launch_bounds__(256) void pack_n(short* __restrict__ dst,
    const float* __restrict__ Wn, int layer)
{
  int id = blockIdx.x * 256 + threadIdx.x;
  int j = id & 7, l = (id >> 3) & 63, kt = (id >> 9) & 7, nt = id >> 12;
  int k = kt * 32 + (l >> 4) * 8 + j;
  int n = nt * 16 + (l & 15);
  dst[id] = f2bf(Wn[((size_t)layer * 512 + 256 + k) * 256 + n]);
}

// ---------------- G0 GEMM: C[M,768] = x[M,128] @ WcF + bc ----------------------
__global__ __launch_bounds__(256) void gemm_g0(
    const float* __restrict__ Ap, const short* __restrict__ BF,
    const float* __restrict__ bias, short* __restrict__ C)
{
  const int tid = threadIdx.x, w = tid >> 6, l = tid & 63;
  const int m0 = blockIdx.x * 64 + w * 16;
  const int nb = blockIdx.y;
  const int K = 128;
  f32x4 zero4 = {0.f, 0.f, 0.f, 0.f};
  f32x4 acc[8];
#pragma unroll
  for (int nt = 0; nt < 8; nt++) acc[nt] = zero4;
#pragma unroll
  for (int kt = 0; kt < 4; kt++){
    const float* A = Ap + (size_t)(m0 + (l & 15)) * K + kt * 32 + (l >> 4) * 8;
    f32x4 a0 = *(const f32x4*)A;
    f32x4 a1 = *(const f32x4*)(A + 4);
    bf16x8 af;
    af[0] = f2bf(a0[0]); af[1] = f2bf(a0[1]); af[2] = f2bf(a0[2]); af[3] = f2bf(a0[3]);
    af[4] = f2bf(a1[0]); af[5] = f2bf(a1[1]); af[6] = f2bf(a1[2]); af[7] = f2bf(a1[3]);
#pragma unroll
    for (int nt = 0; nt < 8; nt++){
      bf16x8 bf = *(const bf16x8*)(BF + (size_t)(((nb * 8 + nt) * 4 + kt) * 64 + l) * 8);
      acc[nt] = MF(af, bf, acc[nt]);
    }
  }
#pragma unroll
  for (int nt = 0; nt < 8; nt++){
    int col = nb * 128 + nt * 16 + (l & 15);
    float bv = bias[col];
#pragma unroll
    for (int rr = 0; rr < 4; rr++){
      int mrow = m0 + (l >> 4) * 4 + rr;
      C[(size_t)mrow * 768 + col] = f2bf(acc[nt][rr] + bv);
    }
  }
}

// ---------------- repack Gbuf -> per-thread 6-value chunks (layer0) ------------
__global__ __launch_bounds__(256) void repack6(const unsigned short* __restrict__ Gbuf,
                                               short* __restrict__ GpA4, unsigned* __restrict__ GpB2)
{
  int id = blockIdx.x * 256 + threadIdx.x;
  int cix = id & 15, wv = (id >> 4) & 7, t = (id >> 7) & 511, row = id >> 16;
  short v[6];
#pragma unroll
  for (int i = 0; i < 2; i++)
#pragma unroll
    for (int g = 0; g < 3; g++)
      v[i * 3 + g] =
        (short)Gbuf[((size_t)row * 512 + t) * 768 + g * 256 + i * 128 + wv * 16 + cix];
  bf16x4 a = {v[0], v[1], v[2], v[3]};
  *(bf16x4*)(GpA4 + (size_t)id * 4) = a;
  GpB2[id] = (unsigned)(unsigned short)v[4] | ((unsigned)(unsigned short)v[5] << 16);
}

// ---------------- fused dual-layer persistent kernel (R9, best known) ----------
__global__ __launch_bounds__(512, 1) void fused_recur(
    const short* __restrict__ GpA4, const unsigned* __restrict__ GpB2,
    const short* __restrict__ WZR0F, const short* __restrict__ WN0F,
    const short* __restrict__ WZR1F, const short* __restrict__ WN1F,
    const short* __restrict__ W1TF, const float* __restrict__ bcat1,
    short* __restrict__ pipe, float* __restrict__ out,
    float* __restrict__ finals, unsigned* __restrict__ flags)
{
  __shared__ __align__(16) char  ldsb[4096];    // h/rA state + zero regions
  __shared__ __align__(16) short wnL[65536];    // layer1 wn frags (128KB)
  __shared__ __align__(16) short p1L[12288];    // layer1 P1 chunk [w][16t][16cix][6]

  const int tid = threadIdx.x;
  const int w = tid >> 6, l = tid & 63;
  const int cix = l & 15, lk = l >> 4;
  const f32x4 Z4 = {0.f, 0.f, 0.f, 0.f};

  *(uint64_t*)(ldsb + tid * 8) = 0ull;

  const int A0 = (cix == 0) ? (lk << 4) : 1024;   // bcast zero for cix>0
  const int col0 = w * 16 + cix, col1 = col0 + 128;
  const int oA00 = col0 * 2, oA10 = col1 * 2;
  float h00 = 0.f, h10 = 0.f;

#define AF_ZR(KT) (*(const bf16x8*)(ldsb + A0 + (KT) * 64))
#define AF_N(KT)  (*(const bf16x8*)(ldsb + A0 + (KT) * 64 + 2048))

  if (blockIdx.x < 128){
    // =================== layer 0 (producer) ===================
    const int r0 = blockIdx.x;
    const int chunkBase = blockIdx.x * 65536 + w * 16 + cix;
    bf16x8 wzr[4][8], wn[2][8];
#pragma unroll
    for (int i = 0; i < 4; i++)
#pragma unroll
      for (int kt = 0; kt < 8; kt++)
        wzr[i][kt] = *(const bf16x8*)(WZR0F + (size_t)((((w + 8 * i) * 8 + kt) * 64 + l) * 8));
#pragma unroll
    for (int i = 0; i < 2; i++)
#pragma unroll
      for (int kt = 0; kt < 8; kt++)
        wn[i][kt] = *(const bf16x8*)(WN0F + (size_t)((((w + 8 * i) * 8 + kt) * 64 + l) * 8));
    __syncthreads();

    bf16x4 rgA0{}, rgA1{};
    unsigned rgB0 = 0, rgB1 = 0;
    if (lk == 0){
      rgA0 = *(const bf16x4*)(GpA4 + (size_t)chunkBase * 4);
      rgB0 = GpB2[chunkBase];
      rgA1 = *(const bf16x4*)(GpA4 + (size_t)(chunkBase + 128) * 4);
      rgB1 = GpB2[chunkBase + 128];
    }

#define STEP0(T, RGA, RGB) do { \
    bf16x8 x0 = AF_ZR(0), x1 = AF_ZR(1), x2 = AF_ZR(2), x3 = AF_ZR(3); \
    f32x4 az0 = Z4, az1 = Z4, ar0 = Z4, ar1 = Z4; \
    __builtin_amdgcn_s_setprio(1); \
    az0 = MF(x0, wzr[0][0], az0); az1 = MF(x0, wzr[1][0], az1); \
    ar0 = MF(x0, wzr[2][0], ar0); ar1 = MF(x0, wzr[3][0], ar1); x0 = AF_ZR(4); \
    az0 = MF(x1, wzr[0][1], az0); az1 = MF(x1, wzr[1][1], az1); \
    ar0 = MF(x1, wzr[2][1], ar0); ar1 = MF(x1, wzr[3][1], ar1); x1 = AF_ZR(5); \
    az0 = MF(x2, wzr[0][2], az0); az1 = MF(x2, wzr[1][2], az1); \
    ar0 = MF(x2, wzr[2][2], ar0); ar1 = MF(x2, wzr[3][2], ar1); x2 = AF_ZR(6); \
    az0 = MF(x3, wzr[0][3], az0); az1 = MF(x3, wzr[1][3], az1); \
    ar0 = MF(x3, wzr[2][3], ar0); ar1 = MF(x3, wzr[3][3], ar1); x3 = AF_ZR(7); \
    az0 = MF(x0, wzr[0][4], az0); az1 = MF(x0, wzr[1][4], az1); \
    ar0 = MF(x0, wzr[2][4], ar0); ar1 = MF(x0, wzr[3][4], ar1); \
    az0 = MF(x1, wzr[0][5], az0); az1 = MF(x1, wzr[1][5], az1); \
    ar0 = MF(x1, wzr[2][5], ar0); ar1 = MF(x1, wzr[3][5], ar1); \
    az0 = MF(x2, wzr[0][6], az0); az1 = MF(x2, wzr[1][6], az1); \
    ar0 = MF(x2, wzr[2][6], ar0); ar1 = MF(x2, wzr[3][6], ar1); \
    az0 = MF(x3, wzr[0][7], az0); az1 = MF(x3, wzr[1][7], az1); \
    ar0 = MF(x3, wzr[2][7], ar0); ar1 = MF(x3, wzr[3][7], ar1); \
    __builtin_amdgcn_s_setprio(0); \
    float gn00 = 0.f, gn10 = 0.f, zv00 = 0.f, zv10 = 0.f; \
    if (lk == 0){ \
      float gz00 = bf2f((unsigned short)RGA[0]), gr00 = bf2f((unsigned short)RGA[1]); \
      gn00 = bf2f((unsigned short)RGA[2]); \
      float gz10 = bf2f((unsigned short)RGA[3]); \
      float gr10 = bf2f((unsigned short)(RGB & 0xffffu)); \
      gn10 = bf2f((unsigned short)(RGB >> 16)); \
      int tn = (T) + 2; if (tn >= S_) tn = (T); \
      size_t ch = (size_t)chunkBase + (size_t)tn * 128; \
      RGA = *(const bf16x4*)(GpA4 + ch * 4); \
      RGB = GpB2[ch]; \
      zv00 = sigmoidf_(az0[0] + gz00); zv10 = sigmoidf_(az1[0] + gz10); \
      float rv00 = sigmoidf_(ar0[0] + gr00), rv10 = sigmoidf_(ar1[0] + gr10); \
      *(short*)(ldsb + 2048 + oA00) = f2bf(rv00 * h00); \
      *(short*)(ldsb + 2048 + oA10) = f2bf(rv10 * h10); \
    } \
    bar_lds(); \
    bf16x8 y0 = AF_N(0), y1 = AF_N(1); \
    f32x4 an0 = Z4, an1 = Z4; \
    __builtin_amdgcn_s_setprio(1); \
    an0 = MF(y0, wn[0][0], an0); an1 = MF(y0, wn[1][0], an1); y0 = AF_N(2); \
    an0 = MF(y1, wn[0][1], an0); an1 = MF(y1, wn[1][1], an1); y1 = AF_N(3); \
    an0 = MF(y0, wn[0][2], an0); an1 = MF(y0, wn[1][2], an1); y0 = AF_N(4); \
    an0 = MF(y1, wn[0][3], an0); an1 = MF(y1, wn[1][3], an1); y1 = AF_N(5); \
    an0 = MF(y0, wn[0][4], an0); an1 = MF(y0, wn[1][4], an1); y0 = AF_N(6); \
    an0 = MF(y1, wn[0][5], an0); an1 = MF(y1, wn[1][5], an1); y1 = AF_N(7); \
    an0 = MF(y0, wn[0][6], an0); an1 = MF(y0, wn[1][6], an1); \
    an0 = MF(y1, wn[0][7], an0); an1 = MF(y1, wn[1][7], an1); \
    __builtin_amdgcn_s_setprio(0); \
    if (lk == 0){ \
      float nv00 = tanhf_(an0[0] + gn00), nv10 = tanhf_(an1[0] + gn10); \
      h00 = (1.f - zv00) * nv00 + zv00 * h00; \
      h10 = (1.f - zv10) * nv10 + zv10 * h10; \
      *(short*)(ldsb + oA00) = f2bf(h00); \
      *(short*)(ldsb + oA10) = f2bf(h10); \
      size_t ob = ((size_t)r0 * S_ + (T)) * H_; \
      pipe[ob + col0] = f2bf(h00); \
      pipe[ob + col1] = f2bf(h10); \
    } \
    bar_lds(); \
  } while (0)

#pragma unroll 1
    for (int t = 0; t < S_; t += 2){
      STEP0(t, rgA0, rgB0);
      STEP0(t + 1, rgA1, rgB1);
      if ((t & 15) == 14){
        __syncthreads();   // drains each wave's vmcnt: all pipe stores in L2
        if (tid == 0)
          __hip_atomic_store(&flags[r0], (unsigned)((t + 2) >> 4),
                             __ATOMIC_RELEASE, __HIP_MEMORY_SCOPE_AGENT);
      }
    }
#undef STEP0
    if (lk == 0){
      finals[(size_t)r0 * H_ + col0] = h00;
      finals[(size_t)r0 * H_ + col1] = h10;
    }
  } else {
    // =================== layer 1 (consumer) ===================
    const int b = blockIdx.x - 128;
    bf16x8 wzr[4][8];
#pragma unroll
    for (int i = 0; i < 4; i++)
#pragma unroll
      for (int kt = 0; kt < 8; kt++)
        wzr[i][kt] = *(const bf16x8*)(WZR1F + (size_t)((((w + 8 * i) * 8 + kt) * 64 + l) * 8));
#pragma unroll
    for (int i = 0; i < 2; i++)
#pragma unroll
      for (int kt = 0; kt < 8; kt++){
        bf16x8 v = *(const bf16x8*)(WN1F + (size_t)((((w + 8 * i) * 8 + kt) * 64 + l) * 8));
        *(bf16x8*)(wnL + (size_t)(((w * 2 + i) * 8 + kt) * 64 + l) * 8) = v;
      }
    __syncthreads();

    const short* wn0p = wnL + (size_t)(w * 2 + 0) * 8 * 512 + l * 8;
    const short* wn1p = wnL + (size_t)(w * 2 + 1) * 8 * 512 + l * 8;
#define WNL0(KT)  (*(const bf16x8*)(wn0p + (KT) * 512))
#define WNL1(KT)  (*(const bf16x8*)(wn1p + (KT) * 512))

    const short* wt0 = W1TF + (size_t)(w)      * 8 * 512 + l * 8;
    const short* wt1 = W1TF + (size_t)(16 + w) * 8 * 512 + l * 8;
    const short* wt2 = W1TF + (size_t)(32 + w) * 8 * 512 + l * 8;
    const short* wt3 = W1TF + (size_t)(8 + w)  * 8 * 512 + l * 8;
    const short* wt4 = W1TF + (size_t)(24 + w) * 8 * 512 + l * 8;
    const short* wt5 = W1TF + (size_t)(40 + w) * 8 * 512 + l * 8;
    float bb0 = bcat1[0 * 256 + 0 + w * 16 + cix];
    float bb1 = bcat1[1 * 256 + 0 + w * 16 + cix];
    float bb2 = bcat1[2 * 256 + 0 + w * 16 + cix];
    float bb3 = bcat1[0 * 256 + 128 + w * 16 + cix];
    float bb4 = bcat1[1 * 256 + 128 + w * 16 + cix];
    float bb5 = bcat1[2 * 256 + 128 + w * 16 + cix];
    short* p1Lw = p1L + w * 1536;   // 16t*16cix*6

#pragma unroll 1
    for (int c = 0; c < 32; c++){
      if (tid == 0){
        unsigned target = (unsigned)(c + 1);
        int guard = 0;
        while (__hip_atomic_load(&flags[b], __ATOMIC_ACQUIRE, __HIP_MEMORY_SCOPE_AGENT) < target){
          __builtin_amdgcn_s_sleep(4);
          if (++guard > (1 << 20)) break;   // bounded: bug -> wrong answer, not hang
        }
      }
      __syncthreads();

      // ---- P1 chunk GEMM: rows = 16 timesteps (full M), K=256, own 6 N-tiles
      const short* hp = pipe + ((size_t)b * 512 + c * 16 + cix) * 256 + lk * 8;
      f32x4 p0 = Z4, p1 = Z4, p2 = Z4, p3 = Z4, p4 = Z4, p5 = Z4;
      bf16x8 a0 = *(const bf16x8*)(hp + 0 * 32), a1 = *(const bf16x8*)(hp + 1 * 32);
      bf16x8 a2 = *(const bf16x8*)(hp + 2 * 32), a3 = *(const bf16x8*)(hp + 3 * 32);
      bf16x8 b0 = *(const bf16x8*)(wt0), b1 = *(const bf16x8*)(wt1), b2 = *(const bf16x8*)(wt2);
      bf16x8 b3 = *(const bf16x8*)(wt3), b4 = *(const bf16x8*)(wt4), b5 = *(const bf16x8*)(wt5);
#define GKT(AX, KTN) \
      p0 = MF(AX, b0, p0); b0 = *(const bf16x8*)(wt0 + (KTN) * 512); \
      p1 = MF(AX, b1, p1); b1 = *(const bf16x8*)(wt1 + (KTN) * 512); \
      p2 = MF(AX, b2, p2); b2 = *(const bf16x8*)(wt2 + (KTN) * 512); \
      p3 = MF(AX, b3, p3); b3 = *(const bf16x8*)(wt3 + (KTN) * 512); \
      p4 = MF(AX, b4, p4); b4 = *(const bf16x8*)(wt4 + (KTN) * 512); \
      p5 = MF(AX, b5, p5); b5 = *(const bf16x8*)(wt5 + (KTN) * 512);
#define GKTL(AX) \
      p0 = MF(AX, b0, p0); p1 = MF(AX, b1, p1); p2 = MF(AX, b2, p2); \
      p3 = MF(AX, b3, p3); p4 = MF(AX, b4, p4); p5 = MF(AX, b5, p5);
      GKT(a0, 1); a0 = *(const bf16x8*)(hp + 4 * 32);
      GKT(a1, 2); a1 = *(const bf16x8*)(hp + 5 * 32);
      GKT(a2, 3); a2 = *(const bf16x8*)(hp + 6 * 32);
      GKT(a3, 4); a3 = *(const bf16x8*)(hp + 7 * 32);
      GKT(a0, 5);
      GKT(a1, 6);
      GKT(a2, 7);
      GKTL(a3);
#undef GKT
#undef GKTL
      // ---- write P1 -> p1L (bf16 pairs), layout [t][cix][6]
#pragma unroll
      for (int r = 0; r < 4; r++){
        int tl = lk * 4 + r;
        int base = (tl * 16 + cix) * 6;
        unsigned u0 = (unsigned)(unsigned short)f2bf(p0[r]) | ((unsigned)(unsigned short)f2bf(p1[r]) << 16);
        unsigned u1 = (unsigned)(unsigned short)f2bf(p2[r]) | ((unsigned)(unsigned short)f2bf(p3[r]) << 16);
        unsigned u2 = (unsigned)(unsigned short)f2bf(p4[r]) | ((unsigned)(unsigned short)f2bf(p5[r]) << 16);
        *(unsigned*)(p1Lw + base)     = u0;
        *(unsigned*)(p1Lw + base + 2) = u1;
        *(unsigned*)(p1Lw + base + 4) = u2;
      }

      // ---- 16 recurrence steps
#pragma unroll 1
      for (int ts = 0; ts < 16; ts++){
        int T = c * 16 + ts;
        float gz00 = 0.f, gr00 = 0.f, gn00 = 0.f, gz10 = 0.f, gr10 = 0.f, gn10 = 0.f;
        if (lk == 0){
          const short* pb = p1Lw + (ts * 16 + cix) * 6;
          unsigned u0 = *(const unsigned*)(pb);
          unsigned u1 = *(const unsigned*)(pb + 2);
          unsigned u2 = *(const unsigned*)(pb + 4);
          gz00 = bf2f((unsigned short)(u0 & 0xffffu)) + bb0;
          gr00 = bf2f((unsigned short)(u0 >> 16)) + bb1;
          gn00 = bf2f((unsigned short)(u1 & 0xffffu)) + bb2;
          gz10 = bf2f((unsigned short)(u1 >> 16)) + bb3;
          gr10 = bf2f((unsigned short)(u2 & 0xffffu)) + bb4;
          gn10 = bf2f((unsigned short)(u2 >> 16)) + bb5;
        }
        bf16x8 x0 = AF_ZR(0), x1 = AF_ZR(1), x2 = AF_ZR(2), x3 = AF_ZR(3);
        f32x4 az0 = Z4, az1 = Z4, ar0 = Z4, ar1 = Z4;
        __builtin_amdgcn_s_setprio(1);
        az0 = MF(x0, wzr[0][0], az0); az1 = MF(x0, wzr[1][0], az1);
        ar0 = MF(x0, wzr[2][0], ar0); ar1 = MF(x0, wzr[3][0], ar1); x0 = AF_ZR(4);
        az0 = MF(x1, wzr[0][1], az0); az1 = MF(x1, wzr[1][1], az1);
        ar0 = MF(x1, wzr[2][1], ar0); ar1 = MF(x1, wzr[3][1], ar1); x1 = AF_ZR(5);
        az0 = MF(x2, wzr[0][2], az0); az1 = MF(x2, wzr[1][2], az1);
        ar0 = MF(x2, wzr[2][2], ar0); ar1 = MF(x2, wzr[3][2], ar1); x2 = AF_ZR(6);
        az0 = MF(x3, wzr[0][3], az0); az1 = MF(x3, wzr[1][3], az1);
        ar0 = MF(x3, wzr[2][3], ar0); ar1 = MF(x3, wzr[3][3], ar1); x3 = AF_ZR(7);
        az0 = MF(x0, wzr[0][4], az0); az1 = MF(x0, wzr[1][4], az1);
        ar0 = MF(x0, wzr[2][4], ar0); ar1 = MF(x0, wzr[3][4], ar1);
        az0 = MF(x1, wzr[0][5], az0); az1 = MF(x1, wzr[1][5], az1);
        ar0 = MF(x1, wzr[2][5], ar0); ar1 = MF(x1, wzr[3][5], ar1);
        az0 = MF(x2, wzr[0][6], az0); az1 = MF(x2, wzr[1][6], az1);
        ar0 = MF(x2, wzr[2][6], ar0); ar1 = MF(x2, wzr[3][6], ar1);
        az0 = MF(x3, wzr[0][7], az0); az1 = MF(x3, wzr[1][7], az1);
        ar0 = MF(x3, wzr[2][7], ar0); ar1 = MF(x3, wzr[3][7], ar1);
        __builtin_amdgcn_s_setprio(0);
        float zv00 = 0.f, zv10 = 0.f;
        if (lk == 0){
          zv00 = sigmoidf_(az0[0] + gz00); zv10 = sigmoidf_(az1[0] + gz10);
          float rv00 = sigmoidf_(ar0[0] + gr00), rv10 = sigmoidf_(ar1[0] + gr10);
          *(short*)(ldsb + 2048 + oA00) = f2bf(rv00 * h00);
          *(short*)(ldsb + 2048 + oA10) = f2bf(rv10 * h10);
        }
        bf16x8 w00 = WNL0(0), w10 = WNL1(0), w01 = WNL0(1), w11 = WNL1(1);
        bar_lds();
        bf16x8 y0 = AF_N(0), y1 = AF_N(1);
        f32x4 an0 = Z4, an1 = Z4;
        __builtin_amdgcn_s_setprio(1);
        an0 = MF(y0, w00, an0); an1 = MF(y0, w10, an1); y0 = AF_N(2); w00 = WNL0(2); w10 = WNL1(2);
        an0 = MF(y1, w01, an0); an1 = MF(y1, w11, an1); y1 = AF_N(3); w01 = WNL0(3); w11 = WNL1(3);
        an0 = MF(y0, w00, an0); an1 = MF(y0, w10, an1); y0 = AF_N(4); w00 = WNL0(4); w10 = WNL1(4);
        an0 = MF(y1, w01, an0); an1 = MF(y1, w11, an1); y1 = AF_N(5); w01 = WNL0(5); w11 = WNL1(5);
        an0 = MF(y0, w00, an0); an1 = MF(y0, w10, an1); y0 = AF_N(6); w00 = WNL0(6); w10 = WNL1(6);
        an0 = MF(y1, w01, an0); an1 = MF(y1, w11, an1); y1 = AF_N(7); w01 = WNL0(7); w11 = WNL1(7);
        an0 = MF(y0, w00, an0); an1 = MF(y0, w10, an1);
        an0 = MF(y1, w01, an0); an1 = MF(y1, w11, an1);
        __builtin_amdgcn_s_setprio(0);
        if (lk == 0){
          float nv00 = tanhf_(an0[0] + gn00), nv10 = tanhf_(an1[0] + gn10);
          h00 = (1.f - zv00) * nv00 + zv00 * h00;
          h10 = (1.f - zv10) * nv10 + zv10 * h10;
          *(short*)(ldsb + oA00) = f2bf(h00);
          *(short*)(ldsb + oA10) = f2bf(h10);
          size_t ob = ((size_t)b * S_ + T) * H_;
          out[ob + col0] = h00;
          out[ob + col1] = h10;
        }
        bar_lds();
      }
    }
#undef WNL0
#undef WNL1
    if (lk == 0){
      finals[32768 + (size_t)b * H_ + col0] = h00;
      finals[32768 + (size_t)b * H_ + col1] = h10;
    }
  }
#undef AF_ZR
#undef AF_N
}

// ---------------- launcher ----------------------------------------------------
extern "C" void kernel_launch(void* const* d_in, const int* in_sizes, int n_in,
                              void* d_out, int out_size, void* d_ws, size_t ws_size,
                              hipStream_t stream)
{
  (void)in_sizes; (void)n_in; (void)out_size; (void)ws_size;
  const float* x    = (const float*)d_in[0];
  const float* W_in = (const float*)d_in[1];
  const float* b_in = (const float*)d_in[2];
  const float* Wz   = (const float*)d_in[3];
  const float* bz   = (const float*)d_in[4];
  const float* Wr   = (const float*)d_in[5];
  const float* br   = (const float*)d_in[6];
  const float* Wn   = (const float*)d_in[7];
  const float* bn   = (const float*)d_in[8];
  float* out = (float*)d_out;

  char* ws = (char*)d_ws;
  short*    Gbuf  = (short*)(ws + 0);            // [65536][768] bf16 (96MB)
  short*    GpA4  = (short*)(ws + 100663296);    // 8.4M chunks * 8B (64MB)
  unsigned* GpB2  = (unsigned*)(ws + 167772160); // 8.4M chunks * 4B (32MB)
  float* WcT   = (float*)(ws + 201326592);
  float* bc    = (float*)(ws + 201719808);
  float* bcat1 = (float*)(ws + 201722880);
  short* WCF   = (short*)(ws + 201725952);
  short* W1TF  = (short*)(ws + 201922560);
  short* WZR0  = (short*)(ws + 202315776);
  short* WN0   = (short*)(ws + 202577920);
  short* WZR1  = (short*)(ws + 202708992);
  short* WN1   = (short*)(ws + 202971136);
  short* pipe  = (short*)(ws + 203102208);       // h0 bf16 [b][t][256] (32MB)
  unsigned* flags = (unsigned*)(ws + 236656640); // [128]

  prep_compute<<<390, 256, 0, stream>>>(W_in, b_in, Wz, bz, Wr, br, Wn, bn, WcT, bc, bcat1);
  pack_wc <<<384, 256, 0, stream>>>(WCF, WcT);
  pack_top<<<768, 256, 0, stream>>>(W1TF, Wz, Wr, Wn);
  pack_zr <<<512, 256, 0, stream>>>(WZR0, Wz, Wr, 0);
  pack_n  <<<256, 256, 0, stream>>>(WN0, Wn, 0);
  pack_zr <<<512, 256, 0, stream>>>(WZR1, Wz, Wr, 1);
  pack_n  <<<256, 256, 0, stream>>>(WN1, Wn, 1);

  gemm_g0<<<dim3(1024, 6), 256, 0, stream>>>(x, WCF, bc, Gbuf);
  repack6<<<32768, 256, 0, stream>>>((const unsigned short*)Gbuf, GpA4, GpB2);
  hipMemsetAsync(flags, 0, 128 * sizeof(unsigned), stream);
  fused_recur<<<256, 512, 0, stream>>>(GpA4, GpB2, WZR0, WN0, WZR1, WN1, W1TF, bcat1,
                                       pipe, out, out + 16777216, flags);
}